// Round 8
// baseline (1533.694 us; speedup 1.0000x reference)
//
#include <hip/hip_runtime.h>
#include <stdint.h>

#define N_NODES 100000
#define FEAT 64
#define SCAN_B 1024
#define BKT 256                                  // dst nodes per bucket
#define NBINS ((N_NODES + BKT - 1) / BKT)        // 391
#define NTILES 256
#define SRC_MASK 0x00FFFFFFu

typedef __attribute__((ext_vector_type(8))) short bf16x8;
typedef __attribute__((ext_vector_type(4))) float f32x4;

// ---- bucket partition build ----

// Per-tile histogram of dst>>8 (LDS atomics only), H[bin][tile] layout.
__global__ __launch_bounds__(256) void tile_hist_kernel(
    const int* __restrict__ dst, int* __restrict__ H, int nE, int tileEdges) {
    __shared__ int hist[NBINS];
    const int tile = blockIdx.x;
    const int tid = threadIdx.x;
    for (int i = tid; i < NBINS; i += 256) hist[i] = 0;
    __syncthreads();
    int e0 = tile * tileEdges;
    int e1 = min(e0 + tileEdges, nE);
    for (int e = e0 + tid; e < e1; e += 256) atomicAdd(&hist[dst[e] >> 8], 1);
    __syncthreads();
    for (int i = tid; i < NBINS; i += 256) H[i * NTILES + tile] = hist[i];
}

// Block-level exclusive scan (Hillis-Steele), partials -> P, totals -> bsum.
__global__ __launch_bounds__(SCAN_B) void scan1_kernel(
    const int* __restrict__ deg, int* __restrict__ P,
    int* __restrict__ bsum, int n) {
    __shared__ int tmp[SCAN_B];
    int t = threadIdx.x;
    int gid = blockIdx.x * SCAN_B + t;
    int v = (gid < n) ? deg[gid] : 0;
    tmp[t] = v;
    __syncthreads();
    for (int off = 1; off < SCAN_B; off <<= 1) {
        int a = (t >= off) ? tmp[t - off] : 0;
        __syncthreads();
        tmp[t] += a;
        __syncthreads();
    }
    if (gid < n) P[gid] = tmp[t] - v;  // exclusive
    if (t == SCAN_B - 1) bsum[blockIdx.x] = tmp[t];
}

// Exclusive scan of <=128 block sums, single block of 128 threads.
__global__ __launch_bounds__(128) void scan2_kernel(int* __restrict__ bsum, int nb) {
    __shared__ int tmp[128];
    int t = threadIdx.x;
    int v = (t < nb) ? bsum[t] : 0;
    tmp[t] = v;
    __syncthreads();
    for (int off = 1; off < 128; off <<= 1) {
        int a = (t >= off) ? tmp[t - off] : 0;
        __syncthreads();
        tmp[t] += a;
        __syncthreads();
    }
    if (t < nb) bsum[t] = tmp[t] - v;  // exclusive
}

// Add block offsets; set P[n]=total.
__global__ __launch_bounds__(256) void scan3_kernel(
    int* __restrict__ P, const int* __restrict__ bsum, int n, int total) {
    int gid = blockIdx.x * blockDim.x + threadIdx.x;
    if (gid < n) P[gid] += bsum[gid >> 10];
    if (gid == 0) P[n] = total;
}

// Scatter edges into bucket segments. Position = P[bin][tile] + LDS-local
// rank -> counting-sort by bucket; writes are ~64B runs, no global atomics.
// Record packs (dst&255)<<24 | src (src < 2^17).
__global__ __launch_bounds__(256) void scatter_bucket_kernel(
    const int* __restrict__ src, const int* __restrict__ dst,
    const int* __restrict__ P, unsigned int* __restrict__ packed,
    int nE, int tileEdges) {
    __shared__ int cur[NBINS];
    const int tile = blockIdx.x;
    const int tid = threadIdx.x;
    for (int i = tid; i < NBINS; i += 256) cur[i] = P[i * NTILES + tile];
    __syncthreads();
    int e0 = tile * tileEdges;
    int e1 = min(e0 + tileEdges, nE);
    for (int e = e0 + tid; e < e1; e += 256) {
        int d = dst[e];
        int pos = atomicAdd(&cur[d >> 8], 1);
        packed[pos] = ((unsigned int)(d & (BKT - 1)) << 24) | (unsigned int)src[e];
    }
}

// Mean aggregation per bucket: acc[256][64] f32 in LDS (64KB). Per edge:
// wave-wide row gather (coalesced 256B) + ds atomicAdd (lane->bank 2-way =
// free). Counts per dst in LDS too. Writeout = coalesced mean.
__global__ __launch_bounds__(512) void bucket_agg_kernel(
    const float* __restrict__ feat,
    const int* __restrict__ P,
    const unsigned int* __restrict__ packed,
    float* __restrict__ mean_out,
    int nE) {
    __shared__ float sAcc[BKT * FEAT];
    __shared__ float sCnt[BKT];
    const int b = blockIdx.x;
    const int tid = threadIdx.x;
    const int lane = tid & 63;
    const int wid = tid >> 6;  // 0..7

    for (int i = tid; i < BKT * FEAT; i += 512) sAcc[i] = 0.f;
    if (tid < BKT) sCnt[tid] = 0.f;
    __syncthreads();

    const int start = P[b * NTILES];
    const int end = (b + 1 < NBINS) ? P[(b + 1) * NTILES] : nE;

    for (int j0 = start + wid * 64; j0 < end; j0 += 8 * 64) {
        int avail = end - j0;
        int cnt = avail < 64 ? avail : 64;
        unsigned int v = (lane < cnt) ? packed[j0 + lane] : 0u;
        int jj = 0;
        for (; jj + 4 <= cnt; jj += 4) {
            unsigned int p0 = __shfl(v, jj + 0), p1 = __shfl(v, jj + 1);
            unsigned int p2 = __shfl(v, jj + 2), p3 = __shfl(v, jj + 3);
            int s0 = p0 & SRC_MASK, s1 = p1 & SRC_MASK;
            int s2 = p2 & SRC_MASK, s3 = p3 & SRC_MASK;
            int d0 = p0 >> 24, d1 = p1 >> 24, d2 = p2 >> 24, d3 = p3 >> 24;
            float f0 = feat[(size_t)s0 * FEAT + lane];
            float f1 = feat[(size_t)s1 * FEAT + lane];
            float f2 = feat[(size_t)s2 * FEAT + lane];
            float f3 = feat[(size_t)s3 * FEAT + lane];
            atomicAdd(&sAcc[d0 * FEAT + lane], f0);
            atomicAdd(&sAcc[d1 * FEAT + lane], f1);
            atomicAdd(&sAcc[d2 * FEAT + lane], f2);
            atomicAdd(&sAcc[d3 * FEAT + lane], f3);
            if (lane < 4) {
                int dd = (lane == 0) ? d0 : (lane == 1) ? d1 : (lane == 2) ? d2 : d3;
                atomicAdd(&sCnt[dd], 1.f);
            }
        }
        for (; jj < cnt; ++jj) {
            unsigned int p = __shfl(v, jj);
            int s = p & SRC_MASK, d = p >> 24;
            float f = feat[(size_t)s * FEAT + lane];
            atomicAdd(&sAcc[d * FEAT + lane], f);
            if (lane == 0) atomicAdd(&sCnt[d], 1.f);
        }
    }
    __syncthreads();

    const int base = b * BKT;
    for (int i = tid; i < BKT * FEAT; i += 512) {
        int node = base + (i >> 6);
        if (node < N_NODES)
            mean_out[(size_t)node * FEAT + (i & 63)] =
                sAcc[i] / fmaxf(sCnt[i >> 6], 1.f);
    }
}

// ---- MFMA linear: out = relu([mean|x] @ [Wl|Wr]^T + b) ----

__device__ __forceinline__ unsigned short f2bf(float f) {
    unsigned int u = __float_as_uint(f);
    u += 0x7fffu + ((u >> 16) & 1u);  // RNE
    return (unsigned short)(u >> 16);
}

__device__ __forceinline__ bf16x8 pack8(const float* __restrict__ p) {
    float4 a = *(const float4*)p;
    float4 b = *(const float4*)(p + 4);
    bf16x8 r;
    r[0] = (short)f2bf(a.x); r[1] = (short)f2bf(a.y);
    r[2] = (short)f2bf(a.z); r[3] = (short)f2bf(a.w);
    r[4] = (short)f2bf(b.x); r[5] = (short)f2bf(b.y);
    r[6] = (short)f2bf(b.z); r[7] = (short)f2bf(b.w);
    return r;
}

// One wave per 16-node group (grid-stride). A = node data (M=16, K=128 =
// [mean|x]), B[k][n] = (k<64?Wl:Wr)[n][k&63]. D (m89): col=l&15, row=(l>>4)*4+reg.
__global__ __launch_bounds__(256) void mfma_linear_kernel(
    const float* __restrict__ mean_in,
    const float* __restrict__ xin,
    const float* __restrict__ Wl,
    const float* __restrict__ bias,
    const float* __restrict__ Wr,
    float* __restrict__ out,
    int nGroups) {
    const int lane = (int)(threadIdx.x & 63);
    const int col = lane & 15;
    const int kg = lane >> 4;

    bf16x8 bfr[4][4];
#pragma unroll
    for (int t = 0; t < 4; ++t) {
        const int n = t * 16 + col;
#pragma unroll
        for (int kk = 0; kk < 4; ++kk) {
            const float* w = (kk < 2 ? Wl : Wr) + n * 64 + (kk & 1) * 32 + kg * 8;
            bfr[t][kk] = pack8(w);
        }
    }
    float bv[4];
#pragma unroll
    for (int t = 0; t < 4; ++t) bv[t] = bias[t * 16 + col];

    const int wave = (int)((blockIdx.x * blockDim.x + threadIdx.x) >> 6);
    const int nWaves = (int)((gridDim.x * blockDim.x) >> 6);

    for (int g = wave; g < nGroups; g += nWaves) {
        const int arow = g * 16 + col;
        const float* mrow = mean_in + (size_t)arow * FEAT + kg * 8;
        const float* xrow = xin + (size_t)arow * FEAT + kg * 8;

        f32x4 acc[4];
#pragma unroll
        for (int t = 0; t < 4; ++t) acc[t] = (f32x4){0.f, 0.f, 0.f, 0.f};

#pragma unroll
        for (int kk = 0; kk < 4; ++kk) {
            const float* p = (kk < 2) ? (mrow + (kk & 1) * 32) : (xrow + (kk & 1) * 32);
            bf16x8 a = pack8(p);
#pragma unroll
            for (int t = 0; t < 4; ++t)
                acc[t] = __builtin_amdgcn_mfma_f32_16x16x32_bf16(a, bfr[t][kk], acc[t], 0, 0, 0);
        }

#pragma unroll
        for (int t = 0; t < 4; ++t) {
#pragma unroll
            for (int r = 0; r < 4; ++r) {
                int node = g * 16 + kg * 4 + r;
                out[(size_t)node * FEAT + t * 16 + col] = fmaxf(acc[t][r] + bv[t], 0.0f);
            }
        }
    }
}

extern "C" void kernel_launch(void* const* d_in, const int* in_sizes, int n_in,
                              void* d_out, int out_size, void* d_ws, size_t ws_size,
                              hipStream_t stream) {
    const float* x   = (const float*)d_in[0];
    const int* ei    = (const int*)d_in[1];
    const float* Wl1 = (const float*)d_in[2];
    const float* b1  = (const float*)d_in[3];
    const float* Wr1 = (const float*)d_in[4];
    const float* Wl2 = (const float*)d_in[5];
    const float* b2  = (const float*)d_in[6];
    const float* Wr2 = (const float*)d_in[7];

    const int E = in_sizes[1] / 2;  // 1,600,000
    const int* src = ei;
    const int* dst = ei + E;
    const int N = N_NODES;

    const int n2 = NBINS * NTILES;                 // 100096
    const int TE = (E + NTILES - 1) / NTILES;      // 6250
    const int NB2 = (n2 + SCAN_B - 1) / SCAN_B;    // 98

    // workspace layout (all counts %4==0 -> meanb stays 16B aligned)
    int* H      = (int*)d_ws;                 // n2
    int* P      = H + n2;                     // n2+1, padded to n2+8
    int* bsum   = P + (n2 + 8);               // 128
    unsigned int* packed = (unsigned int*)(bsum + 128);  // E
    float* meanb = (float*)(packed + E);      // N*64
    float* h    = (float*)d_out;              // hidden buffer lives in d_out
    float* out  = (float*)d_out;

    const int NG = N / 16;  // 6250 MFMA node-groups

    // ---- bucket partition (once, reused by both layers) ----
    tile_hist_kernel<<<NTILES, 256, 0, stream>>>(dst, H, E, TE);
    scan1_kernel<<<NB2, SCAN_B, 0, stream>>>(H, P, bsum, n2);
    scan2_kernel<<<1, 128, 0, stream>>>(bsum, NB2);
    scan3_kernel<<<(n2 + 256) / 256, 256, 0, stream>>>(P, bsum, n2, E);
    scatter_bucket_kernel<<<NTILES, 256, 0, stream>>>(src, dst, P, packed, E, TE);

    // ---- layer 1 ----
    bucket_agg_kernel<<<NBINS, 512, 0, stream>>>(x, P, packed, meanb, E);
    mfma_linear_kernel<<<256, 256, 0, stream>>>(meanb, x, Wl1, b1, Wr1, h, NG);

    // ---- layer 2 ----
    bucket_agg_kernel<<<NBINS, 512, 0, stream>>>(h, P, packed, meanb, E);
    mfma_linear_kernel<<<256, 256, 0, stream>>>(meanb, h, Wl2, b2, Wr2, out, NG);
}

// Round 9
// 204.674 us; speedup vs baseline: 7.4933x; 7.4933x over previous
//
#include <hip/hip_runtime.h>
#include <stdint.h>

#define N_NODES 100000
#define FEAT 64
#define SCAN_B 1024
#define BKT 256                                  // dst nodes per bucket
#define NBINS ((N_NODES + BKT - 1) / BKT)        // 391
#define NTILES 256
#define SRC_MASK 0x00FFFFFFu

typedef __attribute__((ext_vector_type(8))) short bf16x8;
typedef __attribute__((ext_vector_type(4))) float f32x4;

// ---- bucket partition build (proven cheap in R8) ----

// Per-tile histogram of dst>>8 (LDS atomics only), H[bin][tile] layout.
__global__ __launch_bounds__(256) void tile_hist_kernel(
    const int* __restrict__ dst, int* __restrict__ H, int nE, int tileEdges) {
    __shared__ int hist[NBINS];
    const int tile = blockIdx.x;
    const int tid = threadIdx.x;
    for (int i = tid; i < NBINS; i += 256) hist[i] = 0;
    __syncthreads();
    int e0 = tile * tileEdges;
    int e1 = min(e0 + tileEdges, nE);
    for (int e = e0 + tid; e < e1; e += 256) atomicAdd(&hist[dst[e] >> 8], 1);
    __syncthreads();
    for (int i = tid; i < NBINS; i += 256) H[i * NTILES + tile] = hist[i];
}

// Block-level exclusive scan (Hillis-Steele), partials -> P, totals -> bsum.
__global__ __launch_bounds__(SCAN_B) void scan1_kernel(
    const int* __restrict__ deg, int* __restrict__ P,
    int* __restrict__ bsum, int n) {
    __shared__ int tmp[SCAN_B];
    int t = threadIdx.x;
    int gid = blockIdx.x * SCAN_B + t;
    int v = (gid < n) ? deg[gid] : 0;
    tmp[t] = v;
    __syncthreads();
    for (int off = 1; off < SCAN_B; off <<= 1) {
        int a = (t >= off) ? tmp[t - off] : 0;
        __syncthreads();
        tmp[t] += a;
        __syncthreads();
    }
    if (gid < n) P[gid] = tmp[t] - v;  // exclusive
    if (t == SCAN_B - 1) bsum[blockIdx.x] = tmp[t];
}

// Exclusive scan of <=128 block sums, single block of 128 threads.
__global__ __launch_bounds__(128) void scan2_kernel(int* __restrict__ bsum, int nb) {
    __shared__ int tmp[128];
    int t = threadIdx.x;
    int v = (t < nb) ? bsum[t] : 0;
    tmp[t] = v;
    __syncthreads();
    for (int off = 1; off < 128; off <<= 1) {
        int a = (t >= off) ? tmp[t - off] : 0;
        __syncthreads();
        tmp[t] += a;
        __syncthreads();
    }
    if (t < nb) bsum[t] = tmp[t] - v;  // exclusive
}

// Add block offsets; set P[n]=total.
__global__ __launch_bounds__(256) void scan3_kernel(
    int* __restrict__ P, const int* __restrict__ bsum, int n, int total) {
    int gid = blockIdx.x * blockDim.x + threadIdx.x;
    if (gid < n) P[gid] += bsum[gid >> 10];
    if (gid == 0) P[n] = total;
}

// Scatter edges into bucket segments (not yet dst-sorted within bucket).
// Record packs (dst&255)<<24 | src.
__global__ __launch_bounds__(256) void scatter_bucket_kernel(
    const int* __restrict__ src, const int* __restrict__ dst,
    const int* __restrict__ P, unsigned int* __restrict__ packed,
    int nE, int tileEdges) {
    __shared__ int cur[NBINS];
    const int tile = blockIdx.x;
    const int tid = threadIdx.x;
    for (int i = tid; i < NBINS; i += 256) cur[i] = P[i * NTILES + tile];
    __syncthreads();
    int e0 = tile * tileEdges;
    int e1 = min(e0 + tileEdges, nE);
    for (int e = e0 + tid; e < e1; e += 256) {
        int d = dst[e];
        int pos = atomicAdd(&cur[d >> 8], 1);
        packed[pos] = ((unsigned int)(d & (BKT - 1)) << 24) | (unsigned int)src[e];
    }
}

// Local counting sort within each bucket: LDS 256-bin hist -> LDS scan ->
// scatter src ints into the bucket's PRIVATE 16KB window of ssrc (L2-local,
// no cross-XCD line sharing) + exact per-node rowptr.
__global__ __launch_bounds__(256) void bucket_sort_kernel(
    const unsigned int* __restrict__ packed,
    const int* __restrict__ P,
    int* __restrict__ rowptr,
    int* __restrict__ ssrc,
    int nE) {
    __shared__ int hist[BKT];
    __shared__ int cur[BKT];
    const int b = blockIdx.x;
    const int tid = threadIdx.x;

    hist[tid] = 0;
    __syncthreads();
    const int start = P[b * NTILES];
    const int end = (b + 1 < NBINS) ? P[(b + 1) * NTILES] : nE;
    for (int j = start + tid; j < end; j += 256)
        atomicAdd(&hist[packed[j] >> 24], 1);
    __syncthreads();

    // inclusive Hillis-Steele scan of hist
    int v = hist[tid];
    for (int off = 1; off < 256; off <<= 1) {
        int a = (tid >= off) ? hist[tid - off] : 0;
        __syncthreads();
        hist[tid] += a;
        __syncthreads();
    }
    int excl = hist[tid] - v;

    int node = b * BKT + tid;
    if (node <= N_NODES) rowptr[node] = start + excl;  // node==N -> rowptr[N]=E (v=0 tail)
    cur[tid] = start + excl;
    __syncthreads();

    for (int j = start + tid; j < end; j += 256) {
        unsigned int p = packed[j];
        int pos = atomicAdd(&cur[p >> 24], 1);
        ssrc[pos] = (int)(p & SRC_MASK);
    }
}

// Mean aggregation: one quarter-wave (16 lanes) per node, float4 per lane.
// 4 nodes/wave + 4x unroll -> 16 independent row loads in flight per wave.
__global__ __launch_bounds__(256) void agg_kernel(
    const float* __restrict__ feat,
    const int* __restrict__ rowptr,
    const int* __restrict__ ssrc,
    float* __restrict__ mean_out,
    int nNodes) {
    int tid = blockIdx.x * blockDim.x + threadIdx.x;
    int node = tid >> 4;
    if (node >= nNodes) return;
    int chunk = threadIdx.x & 15;
    const float4* feat4 = (const float4*)feat;

    int beg = rowptr[node];
    int end = rowptr[node + 1];
    float4 acc = make_float4(0.f, 0.f, 0.f, 0.f);

    int j = beg;
    for (; j + 4 <= end; j += 4) {
        int s0 = ssrc[j + 0];
        int s1 = ssrc[j + 1];
        int s2 = ssrc[j + 2];
        int s3 = ssrc[j + 3];
        float4 a0 = feat4[(size_t)s0 * 16 + chunk];
        float4 a1 = feat4[(size_t)s1 * 16 + chunk];
        float4 a2 = feat4[(size_t)s2 * 16 + chunk];
        float4 a3 = feat4[(size_t)s3 * 16 + chunk];
        acc.x += (a0.x + a1.x) + (a2.x + a3.x);
        acc.y += (a0.y + a1.y) + (a2.y + a3.y);
        acc.z += (a0.z + a1.z) + (a2.z + a3.z);
        acc.w += (a0.w + a1.w) + (a2.w + a3.w);
    }
    for (; j < end; ++j) {
        int s = ssrc[j];
        float4 a = feat4[(size_t)s * 16 + chunk];
        acc.x += a.x; acc.y += a.y; acc.z += a.z; acc.w += a.w;
    }

    int deg = end - beg;
    float inv = 1.0f / (float)(deg > 0 ? deg : 1);
    float4 m = make_float4(acc.x * inv, acc.y * inv, acc.z * inv, acc.w * inv);
    ((float4*)mean_out)[(size_t)node * 16 + chunk] = m;
}

// ---- MFMA linear: out = relu([mean|x] @ [Wl|Wr]^T + b) ----

__device__ __forceinline__ unsigned short f2bf(float f) {
    unsigned int u = __float_as_uint(f);
    u += 0x7fffu + ((u >> 16) & 1u);  // RNE
    return (unsigned short)(u >> 16);
}

__device__ __forceinline__ bf16x8 pack8(const float* __restrict__ p) {
    float4 a = *(const float4*)p;
    float4 b = *(const float4*)(p + 4);
    bf16x8 r;
    r[0] = (short)f2bf(a.x); r[1] = (short)f2bf(a.y);
    r[2] = (short)f2bf(a.z); r[3] = (short)f2bf(a.w);
    r[4] = (short)f2bf(b.x); r[5] = (short)f2bf(b.y);
    r[6] = (short)f2bf(b.z); r[7] = (short)f2bf(b.w);
    return r;
}

// One wave per 16-node group (grid-stride). A = node data (M=16, K=128 =
// [mean|x]), B[k][n] = (k<64?Wl:Wr)[n][k&63]. D (m89): col=l&15, row=(l>>4)*4+reg.
__global__ __launch_bounds__(256) void mfma_linear_kernel(
    const float* __restrict__ mean_in,
    const float* __restrict__ xin,
    const float* __restrict__ Wl,
    const float* __restrict__ bias,
    const float* __restrict__ Wr,
    float* __restrict__ out,
    int nGroups) {
    const int lane = (int)(threadIdx.x & 63);
    const int col = lane & 15;
    const int kg = lane >> 4;

    bf16x8 bfr[4][4];
#pragma unroll
    for (int t = 0; t < 4; ++t) {
        const int n = t * 16 + col;
#pragma unroll
        for (int kk = 0; kk < 4; ++kk) {
            const float* w = (kk < 2 ? Wl : Wr) + n * 64 + (kk & 1) * 32 + kg * 8;
            bfr[t][kk] = pack8(w);
        }
    }
    float bv[4];
#pragma unroll
    for (int t = 0; t < 4; ++t) bv[t] = bias[t * 16 + col];

    const int wave = (int)((blockIdx.x * blockDim.x + threadIdx.x) >> 6);
    const int nWaves = (int)((gridDim.x * blockDim.x) >> 6);

    for (int g = wave; g < nGroups; g += nWaves) {
        const int arow = g * 16 + col;
        const float* mrow = mean_in + (size_t)arow * FEAT + kg * 8;
        const float* xrow = xin + (size_t)arow * FEAT + kg * 8;

        f32x4 acc[4];
#pragma unroll
        for (int t = 0; t < 4; ++t) acc[t] = (f32x4){0.f, 0.f, 0.f, 0.f};

#pragma unroll
        for (int kk = 0; kk < 4; ++kk) {
            const float* p = (kk < 2) ? (mrow + (kk & 1) * 32) : (xrow + (kk & 1) * 32);
            bf16x8 a = pack8(p);
#pragma unroll
            for (int t = 0; t < 4; ++t)
                acc[t] = __builtin_amdgcn_mfma_f32_16x16x32_bf16(a, bfr[t][kk], acc[t], 0, 0, 0);
        }

#pragma unroll
        for (int t = 0; t < 4; ++t) {
#pragma unroll
            for (int r = 0; r < 4; ++r) {
                int node = g * 16 + kg * 4 + r;
                out[(size_t)node * FEAT + t * 16 + col] = fmaxf(acc[t][r] + bv[t], 0.0f);
            }
        }
    }
}

extern "C" void kernel_launch(void* const* d_in, const int* in_sizes, int n_in,
                              void* d_out, int out_size, void* d_ws, size_t ws_size,
                              hipStream_t stream) {
    const float* x   = (const float*)d_in[0];
    const int* ei    = (const int*)d_in[1];
    const float* Wl1 = (const float*)d_in[2];
    const float* b1  = (const float*)d_in[3];
    const float* Wr1 = (const float*)d_in[4];
    const float* Wl2 = (const float*)d_in[5];
    const float* b2  = (const float*)d_in[6];
    const float* Wr2 = (const float*)d_in[7];

    const int E = in_sizes[1] / 2;  // 1,600,000
    const int* src = ei;
    const int* dst = ei + E;
    const int N = N_NODES;

    const int n2 = NBINS * NTILES;                 // 100096
    const int TE = (E + NTILES - 1) / NTILES;      // 6250
    const int NB2 = (n2 + SCAN_B - 1) / SCAN_B;    // 98

    // workspace layout (int counts all %4==0 -> meanb 16B-aligned)
    int* H      = (int*)d_ws;                        // n2
    int* P      = H + n2;                            // n2+8
    int* bsum   = P + (n2 + 8);                      // 128
    unsigned int* packed = (unsigned int*)(bsum + 128);  // E
    int* rowptr = (int*)(packed + E);                // N+8
    int* ssrc   = rowptr + (N + 8);                  // E
    float* meanb = (float*)(ssrc + E);               // N*64
    float* h    = (float*)d_out;                     // hidden buffer in d_out
    float* out  = (float*)d_out;

    const int NG = N / 16;  // 6250 MFMA node-groups

    // ---- partition + exact sort (once, reused by both layers) ----
    tile_hist_kernel<<<NTILES, 256, 0, stream>>>(dst, H, E, TE);
    scan1_kernel<<<NB2, SCAN_B, 0, stream>>>(H, P, bsum, n2);
    scan2_kernel<<<1, 128, 0, stream>>>(bsum, NB2);
    scan3_kernel<<<(n2 + 256) / 256, 256, 0, stream>>>(P, bsum, n2, E);
    scatter_bucket_kernel<<<NTILES, 256, 0, stream>>>(src, dst, P, packed, E, TE);
    bucket_sort_kernel<<<NBINS, 256, 0, stream>>>(packed, P, rowptr, ssrc, E);

    // ---- layer 1 ----
    agg_kernel<<<(N * 16 + 255) / 256, 256, 0, stream>>>(x, rowptr, ssrc, meanb, N);
    mfma_linear_kernel<<<256, 256, 0, stream>>>(meanb, x, Wl1, b1, Wr1, h, NG);

    // ---- layer 2 ----
    agg_kernel<<<(N * 16 + 255) / 256, 256, 0, stream>>>(h, rowptr, ssrc, meanb, N);
    mfma_linear_kernel<<<256, 256, 0, stream>>>(meanb, h, Wl2, b2, Wr2, out, NG);
}

// Round 10
// 183.040 us; speedup vs baseline: 8.3790x; 1.1182x over previous
//
#include <hip/hip_runtime.h>
#include <stdint.h>

#define N_NODES 100000
#define FEAT 64
#define SCAN_B 1024
#define BKT 256                                  // dst nodes per bucket
#define NBINS ((N_NODES + BKT - 1) / BKT)        // 391
#define NTILES 256
#define SRC_MASK 0x00FFFFFFu

typedef __attribute__((ext_vector_type(8))) short bf16x8;
typedef __attribute__((ext_vector_type(4))) float f32x4;

__device__ __forceinline__ unsigned short f2bf(float f) {
    unsigned int u = __float_as_uint(f);
    u += 0x7fffu + ((u >> 16) & 1u);  // RNE
    return (unsigned short)(u >> 16);
}

// ---- one-time fp32 -> bf16 feature conversion ----
__global__ __launch_bounds__(256) void cvt_bf16_kernel(
    const float* __restrict__ in, unsigned short* __restrict__ out, int n8) {
    int i = blockIdx.x * blockDim.x + threadIdx.x;
    if (i >= n8) return;
    float4 a = ((const float4*)in)[i * 2];
    float4 b = ((const float4*)in)[i * 2 + 1];
    uint4 r;
    r.x = (unsigned int)f2bf(a.x) | ((unsigned int)f2bf(a.y) << 16);
    r.y = (unsigned int)f2bf(a.z) | ((unsigned int)f2bf(a.w) << 16);
    r.z = (unsigned int)f2bf(b.x) | ((unsigned int)f2bf(b.y) << 16);
    r.w = (unsigned int)f2bf(b.z) | ((unsigned int)f2bf(b.w) << 16);
    ((uint4*)out)[i] = r;
}

// ---- bucket partition build (proven cheap in R8/R9) ----

__global__ __launch_bounds__(256) void tile_hist_kernel(
    const int* __restrict__ dst, int* __restrict__ H, int nE, int tileEdges) {
    __shared__ int hist[NBINS];
    const int tile = blockIdx.x;
    const int tid = threadIdx.x;
    for (int i = tid; i < NBINS; i += 256) hist[i] = 0;
    __syncthreads();
    int e0 = tile * tileEdges;
    int e1 = min(e0 + tileEdges, nE);
    for (int e = e0 + tid; e < e1; e += 256) atomicAdd(&hist[dst[e] >> 8], 1);
    __syncthreads();
    for (int i = tid; i < NBINS; i += 256) H[i * NTILES + tile] = hist[i];
}

__global__ __launch_bounds__(SCAN_B) void scan1_kernel(
    const int* __restrict__ deg, int* __restrict__ P,
    int* __restrict__ bsum, int n) {
    __shared__ int tmp[SCAN_B];
    int t = threadIdx.x;
    int gid = blockIdx.x * SCAN_B + t;
    int v = (gid < n) ? deg[gid] : 0;
    tmp[t] = v;
    __syncthreads();
    for (int off = 1; off < SCAN_B; off <<= 1) {
        int a = (t >= off) ? tmp[t - off] : 0;
        __syncthreads();
        tmp[t] += a;
        __syncthreads();
    }
    if (gid < n) P[gid] = tmp[t] - v;  // exclusive
    if (t == SCAN_B - 1) bsum[blockIdx.x] = tmp[t];
}

__global__ __launch_bounds__(128) void scan2_kernel(int* __restrict__ bsum, int nb) {
    __shared__ int tmp[128];
    int t = threadIdx.x;
    int v = (t < nb) ? bsum[t] : 0;
    tmp[t] = v;
    __syncthreads();
    for (int off = 1; off < 128; off <<= 1) {
        int a = (t >= off) ? tmp[t - off] : 0;
        __syncthreads();
        tmp[t] += a;
        __syncthreads();
    }
    if (t < nb) bsum[t] = tmp[t] - v;  // exclusive
}

__global__ __launch_bounds__(256) void scan3_kernel(
    int* __restrict__ P, const int* __restrict__ bsum, int n, int total) {
    int gid = blockIdx.x * blockDim.x + threadIdx.x;
    if (gid < n) P[gid] += bsum[gid >> 10];
    if (gid == 0) P[n] = total;
}

__global__ __launch_bounds__(256) void scatter_bucket_kernel(
    const int* __restrict__ src, const int* __restrict__ dst,
    const int* __restrict__ P, unsigned int* __restrict__ packed,
    int nE, int tileEdges) {
    __shared__ int cur[NBINS];
    const int tile = blockIdx.x;
    const int tid = threadIdx.x;
    for (int i = tid; i < NBINS; i += 256) cur[i] = P[i * NTILES + tile];
    __syncthreads();
    int e0 = tile * tileEdges;
    int e1 = min(e0 + tileEdges, nE);
    for (int e = e0 + tid; e < e1; e += 256) {
        int d = dst[e];
        int pos = atomicAdd(&cur[d >> 8], 1);
        packed[pos] = ((unsigned int)(d & (BKT - 1)) << 24) | (unsigned int)src[e];
    }
}

// Local counting sort within each bucket -> exact dst-sorted ssrc + rowptr.
__global__ __launch_bounds__(256) void bucket_sort_kernel(
    const unsigned int* __restrict__ packed,
    const int* __restrict__ P,
    int* __restrict__ rowptr,
    int* __restrict__ ssrc,
    int nE) {
    __shared__ int hist[BKT];
    __shared__ int cur[BKT];
    const int b = blockIdx.x;
    const int tid = threadIdx.x;

    hist[tid] = 0;
    __syncthreads();
    const int start = P[b * NTILES];
    const int end = (b + 1 < NBINS) ? P[(b + 1) * NTILES] : nE;
    for (int j = start + tid; j < end; j += 256)
        atomicAdd(&hist[packed[j] >> 24], 1);
    __syncthreads();

    int v = hist[tid];
    for (int off = 1; off < 256; off <<= 1) {
        int a = (tid >= off) ? hist[tid - off] : 0;
        __syncthreads();
        hist[tid] += a;
        __syncthreads();
    }
    int excl = hist[tid] - v;

    int node = b * BKT + tid;
    if (node <= N_NODES) rowptr[node] = start + excl;
    cur[tid] = start + excl;
    __syncthreads();

    for (int j = start + tid; j < end; j += 256) {
        unsigned int p = packed[j];
        int pos = atomicAdd(&cur[p >> 24], 1);
        ssrc[pos] = (int)(p & SRC_MASK);
    }
}

// Mean aggregation over bf16 features: 8 lanes per node (16B each), 4x
// unroll -> 32 independent 16B requests in flight per wave. fp32 accum,
// bf16 mean out.
__global__ __launch_bounds__(256) void agg_bf16_kernel(
    const unsigned short* __restrict__ featb,   // [N][64] bf16
    const int* __restrict__ rowptr,
    const int* __restrict__ ssrc,
    unsigned short* __restrict__ meanb,         // [N][64] bf16
    int nNodes) {
    int tid = blockIdx.x * blockDim.x + threadIdx.x;
    int node = tid >> 3;
    if (node >= nNodes) return;
    int chunk = tid & 7;  // 8 lanes/node, 16B (8 bf16) each
    const uint4* feat16 = (const uint4*)featb;  // row = 8 x uint4

    int beg = rowptr[node];
    int end = rowptr[node + 1];
    float acc0 = 0.f, acc1 = 0.f, acc2 = 0.f, acc3 = 0.f;
    float acc4 = 0.f, acc5 = 0.f, acc6 = 0.f, acc7 = 0.f;

#define ADDROW(a)                                         \
    acc0 += __uint_as_float((a).x << 16);                 \
    acc1 += __uint_as_float((a).x & 0xffff0000u);         \
    acc2 += __uint_as_float((a).y << 16);                 \
    acc3 += __uint_as_float((a).y & 0xffff0000u);         \
    acc4 += __uint_as_float((a).z << 16);                 \
    acc5 += __uint_as_float((a).z & 0xffff0000u);         \
    acc6 += __uint_as_float((a).w << 16);                 \
    acc7 += __uint_as_float((a).w & 0xffff0000u);

    int j = beg;
    for (; j + 4 <= end; j += 4) {
        int s0 = ssrc[j + 0];
        int s1 = ssrc[j + 1];
        int s2 = ssrc[j + 2];
        int s3 = ssrc[j + 3];
        uint4 a0 = feat16[(size_t)s0 * 8 + chunk];
        uint4 a1 = feat16[(size_t)s1 * 8 + chunk];
        uint4 a2 = feat16[(size_t)s2 * 8 + chunk];
        uint4 a3 = feat16[(size_t)s3 * 8 + chunk];
        ADDROW(a0) ADDROW(a1) ADDROW(a2) ADDROW(a3)
    }
    for (; j < end; ++j) {
        uint4 a = feat16[(size_t)ssrc[j] * 8 + chunk];
        ADDROW(a)
    }
#undef ADDROW

    int deg = end - beg;
    float inv = 1.0f / (float)(deg > 0 ? deg : 1);
    uint4 r;
    r.x = (unsigned int)f2bf(acc0 * inv) | ((unsigned int)f2bf(acc1 * inv) << 16);
    r.y = (unsigned int)f2bf(acc2 * inv) | ((unsigned int)f2bf(acc3 * inv) << 16);
    r.z = (unsigned int)f2bf(acc4 * inv) | ((unsigned int)f2bf(acc5 * inv) << 16);
    r.w = (unsigned int)f2bf(acc6 * inv) | ((unsigned int)f2bf(acc7 * inv) << 16);
    ((uint4*)meanb)[(size_t)node * 8 + chunk] = r;
}

// ---- MFMA linear: out = relu([mean|x] @ [Wl|Wr]^T + b) ----
// A-fragments load bf16 directly (no conversion). B packed from fp32 once.
// OUT_BF16: layer-1 writes bf16 h; else fp32 (final output).

__device__ __forceinline__ bf16x8 pack8(const float* __restrict__ p) {
    float4 a = *(const float4*)p;
    float4 b = *(const float4*)(p + 4);
    bf16x8 r;
    r[0] = (short)f2bf(a.x); r[1] = (short)f2bf(a.y);
    r[2] = (short)f2bf(a.z); r[3] = (short)f2bf(a.w);
    r[4] = (short)f2bf(b.x); r[5] = (short)f2bf(b.y);
    r[6] = (short)f2bf(b.z); r[7] = (short)f2bf(b.w);
    return r;
}

template <bool OUT_BF16>
__global__ __launch_bounds__(256) void mfma_linear_kernel(
    const unsigned short* __restrict__ meanb,  // [N][64] bf16
    const unsigned short* __restrict__ xb,     // [N][64] bf16
    const float* __restrict__ Wl,
    const float* __restrict__ bias,
    const float* __restrict__ Wr,
    void* __restrict__ outp,
    int nGroups) {
    const int lane = (int)(threadIdx.x & 63);
    const int col = lane & 15;
    const int kg = lane >> 4;

    bf16x8 bfr[4][4];
#pragma unroll
    for (int t = 0; t < 4; ++t) {
        const int n = t * 16 + col;
#pragma unroll
        for (int kk = 0; kk < 4; ++kk) {
            const float* w = (kk < 2 ? Wl : Wr) + n * 64 + (kk & 1) * 32 + kg * 8;
            bfr[t][kk] = pack8(w);
        }
    }
    float bv[4];
#pragma unroll
    for (int t = 0; t < 4; ++t) bv[t] = bias[t * 16 + col];

    const int wave = (int)((blockIdx.x * blockDim.x + threadIdx.x) >> 6);
    const int nWaves = (int)((gridDim.x * blockDim.x) >> 6);

    for (int g = wave; g < nGroups; g += nWaves) {
        const int arow = g * 16 + col;
        const unsigned short* mrow = meanb + (size_t)arow * FEAT + kg * 8;
        const unsigned short* xrow = xb + (size_t)arow * FEAT + kg * 8;

        f32x4 acc[4];
#pragma unroll
        for (int t = 0; t < 4; ++t) acc[t] = (f32x4){0.f, 0.f, 0.f, 0.f};

#pragma unroll
        for (int kk = 0; kk < 4; ++kk) {
            const unsigned short* p =
                (kk < 2) ? (mrow + (kk & 1) * 32) : (xrow + (kk & 1) * 32);
            bf16x8 a = *(const bf16x8*)p;
#pragma unroll
            for (int t = 0; t < 4; ++t)
                acc[t] = __builtin_amdgcn_mfma_f32_16x16x32_bf16(a, bfr[t][kk], acc[t], 0, 0, 0);
        }

#pragma unroll
        for (int t = 0; t < 4; ++t) {
#pragma unroll
            for (int r = 0; r < 4; ++r) {
                int node = g * 16 + kg * 4 + r;
                float v = fmaxf(acc[t][r] + bv[t], 0.0f);
                if (OUT_BF16)
                    ((unsigned short*)outp)[(size_t)node * FEAT + t * 16 + col] = f2bf(v);
                else
                    ((float*)outp)[(size_t)node * FEAT + t * 16 + col] = v;
            }
        }
    }
}

extern "C" void kernel_launch(void* const* d_in, const int* in_sizes, int n_in,
                              void* d_out, int out_size, void* d_ws, size_t ws_size,
                              hipStream_t stream) {
    const float* x   = (const float*)d_in[0];
    const int* ei    = (const int*)d_in[1];
    const float* Wl1 = (const float*)d_in[2];
    const float* b1  = (const float*)d_in[3];
    const float* Wr1 = (const float*)d_in[4];
    const float* Wl2 = (const float*)d_in[5];
    const float* b2  = (const float*)d_in[6];
    const float* Wr2 = (const float*)d_in[7];

    const int E = in_sizes[1] / 2;  // 1,600,000
    const int* src = ei;
    const int* dst = ei + E;
    const int N = N_NODES;

    const int n2 = NBINS * NTILES;               // 100096
    const int TE = (E + NTILES - 1) / NTILES;    // 6250
    const int NB2 = (n2 + SCAN_B - 1) / SCAN_B;  // 98

    // workspace layout (int-counts %4==0 -> every bf16 buffer 16B-aligned)
    int* H      = (int*)d_ws;                            // n2
    int* P      = H + n2;                                // n2+8
    int* bsum   = P + (n2 + 8);                          // 128
    unsigned int* packed = (unsigned int*)(bsum + 128);  // E
    int* rowptr = (int*)(packed + E);                    // N+8
    int* ssrc   = rowptr + (N + 8);                      // E
    unsigned short* meanb = (unsigned short*)(ssrc + E); // N*64 bf16
    unsigned short* xb    = meanb + (size_t)N * FEAT;    // N*64 bf16
    unsigned short* hb    = xb + (size_t)N * FEAT;       // N*64 bf16
    float* out  = (float*)d_out;

    const int NG = N / 16;  // 6250 MFMA node-groups

    // ---- feature conversion + partition/sort (reused by both layers) ----
    cvt_bf16_kernel<<<(N * FEAT / 8 + 255) / 256, 256, 0, stream>>>(x, xb, N * FEAT / 8);
    tile_hist_kernel<<<NTILES, 256, 0, stream>>>(dst, H, E, TE);
    scan1_kernel<<<NB2, SCAN_B, 0, stream>>>(H, P, bsum, n2);
    scan2_kernel<<<1, 128, 0, stream>>>(bsum, NB2);
    scan3_kernel<<<(n2 + 256) / 256, 256, 0, stream>>>(P, bsum, n2, E);
    scatter_bucket_kernel<<<NTILES, 256, 0, stream>>>(src, dst, P, packed, E, TE);
    bucket_sort_kernel<<<NBINS, 256, 0, stream>>>(packed, P, rowptr, ssrc, E);

    // ---- layer 1 ----
    agg_bf16_kernel<<<(N * 8 + 255) / 256, 256, 0, stream>>>(xb, rowptr, ssrc, meanb, N);
    mfma_linear_kernel<true><<<256, 256, 0, stream>>>(meanb, xb, Wl1, b1, Wr1, hb, NG);

    // ---- layer 2 ----
    agg_bf16_kernel<<<(N * 8 + 255) / 256, 256, 0, stream>>>(hb, rowptr, ssrc, meanb, N);
    mfma_linear_kernel<false><<<256, 256, 0, stream>>>(meanb, hb, Wl2, b2, Wr2, out, NG);
}

// Round 11
// 180.907 us; speedup vs baseline: 8.4778x; 1.0118x over previous
//
#include <hip/hip_runtime.h>
#include <stdint.h>

#define N_NODES 100000
#define FEAT 64
#define SCAN_B 1024
#define BKT 256                                  // dst nodes per bucket
#define NBINS ((N_NODES + BKT - 1) / BKT)        // 391
#define NTILES 256
#define SRC_MASK 0x00FFFFFFu

typedef __attribute__((ext_vector_type(8))) short bf16x8;
typedef __attribute__((ext_vector_type(4))) float f32x4;

__device__ __forceinline__ unsigned short f2bf(float f) {
    unsigned int u = __float_as_uint(f);
    u += 0x7fffu + ((u >> 16) & 1u);  // RNE
    return (unsigned short)(u >> 16);
}

// ---- one-time fp32 -> bf16 feature conversion ----
__global__ __launch_bounds__(256) void cvt_bf16_kernel(
    const float* __restrict__ in, unsigned short* __restrict__ out, int n8) {
    int i = blockIdx.x * blockDim.x + threadIdx.x;
    if (i >= n8) return;
    float4 a = ((const float4*)in)[i * 2];
    float4 b = ((const float4*)in)[i * 2 + 1];
    uint4 r;
    r.x = (unsigned int)f2bf(a.x) | ((unsigned int)f2bf(a.y) << 16);
    r.y = (unsigned int)f2bf(a.z) | ((unsigned int)f2bf(a.w) << 16);
    r.z = (unsigned int)f2bf(b.x) | ((unsigned int)f2bf(b.y) << 16);
    r.w = (unsigned int)f2bf(b.z) | ((unsigned int)f2bf(b.w) << 16);
    ((uint4*)out)[i] = r;
}

// ---- bucket partition build (proven cheap in R8/R9) ----

__global__ __launch_bounds__(256) void tile_hist_kernel(
    const int* __restrict__ dst, int* __restrict__ H, int nE, int tileEdges) {
    __shared__ int hist[NBINS];
    const int tile = blockIdx.x;
    const int tid = threadIdx.x;
    for (int i = tid; i < NBINS; i += 256) hist[i] = 0;
    __syncthreads();
    int e0 = tile * tileEdges;
    int e1 = min(e0 + tileEdges, nE);
    for (int e = e0 + tid; e < e1; e += 256) atomicAdd(&hist[dst[e] >> 8], 1);
    __syncthreads();
    for (int i = tid; i < NBINS; i += 256) H[i * NTILES + tile] = hist[i];
}

__global__ __launch_bounds__(SCAN_B) void scan1_kernel(
    const int* __restrict__ deg, int* __restrict__ P,
    int* __restrict__ bsum, int n) {
    __shared__ int tmp[SCAN_B];
    int t = threadIdx.x;
    int gid = blockIdx.x * SCAN_B + t;
    int v = (gid < n) ? deg[gid] : 0;
    tmp[t] = v;
    __syncthreads();
    for (int off = 1; off < SCAN_B; off <<= 1) {
        int a = (t >= off) ? tmp[t - off] : 0;
        __syncthreads();
        tmp[t] += a;
        __syncthreads();
    }
    if (gid < n) P[gid] = tmp[t] - v;  // exclusive
    if (t == SCAN_B - 1) bsum[blockIdx.x] = tmp[t];
}

__global__ __launch_bounds__(128) void scan2_kernel(int* __restrict__ bsum, int nb) {
    __shared__ int tmp[128];
    int t = threadIdx.x;
    int v = (t < nb) ? bsum[t] : 0;
    tmp[t] = v;
    __syncthreads();
    for (int off = 1; off < 128; off <<= 1) {
        int a = (t >= off) ? tmp[t - off] : 0;
        __syncthreads();
        tmp[t] += a;
        __syncthreads();
    }
    if (t < nb) bsum[t] = tmp[t] - v;  // exclusive
}

__global__ __launch_bounds__(256) void scan3_kernel(
    int* __restrict__ P, const int* __restrict__ bsum, int n, int total) {
    int gid = blockIdx.x * blockDim.x + threadIdx.x;
    if (gid < n) P[gid] += bsum[gid >> 10];
    if (gid == 0) P[n] = total;
}

__global__ __launch_bounds__(256) void scatter_bucket_kernel(
    const int* __restrict__ src, const int* __restrict__ dst,
    const int* __restrict__ P, unsigned int* __restrict__ packed,
    int nE, int tileEdges) {
    __shared__ int cur[NBINS];
    const int tile = blockIdx.x;
    const int tid = threadIdx.x;
    for (int i = tid; i < NBINS; i += 256) cur[i] = P[i * NTILES + tile];
    __syncthreads();
    int e0 = tile * tileEdges;
    int e1 = min(e0 + tileEdges, nE);
    for (int e = e0 + tid; e < e1; e += 256) {
        int d = dst[e];
        int pos = atomicAdd(&cur[d >> 8], 1);
        packed[pos] = ((unsigned int)(d & (BKT - 1)) << 24) | (unsigned int)src[e];
    }
}

// Local counting sort within each bucket -> exact dst-sorted ssrc + rowptr.
__global__ __launch_bounds__(256) void bucket_sort_kernel(
    const unsigned int* __restrict__ packed,
    const int* __restrict__ P,
    int* __restrict__ rowptr,
    int* __restrict__ ssrc,
    int nE) {
    __shared__ int hist[BKT];
    __shared__ int cur[BKT];
    const int b = blockIdx.x;
    const int tid = threadIdx.x;

    hist[tid] = 0;
    __syncthreads();
    const int start = P[b * NTILES];
    const int end = (b + 1 < NBINS) ? P[(b + 1) * NTILES] : nE;
    for (int j = start + tid; j < end; j += 256)
        atomicAdd(&hist[packed[j] >> 24], 1);
    __syncthreads();

    int v = hist[tid];
    for (int off = 1; off < 256; off <<= 1) {
        int a = (tid >= off) ? hist[tid - off] : 0;
        __syncthreads();
        hist[tid] += a;
        __syncthreads();
    }
    int excl = hist[tid] - v;

    int node = b * BKT + tid;
    if (node <= N_NODES) rowptr[node] = start + excl;
    cur[tid] = start + excl;
    __syncthreads();

    for (int j = start + tid; j < end; j += 256) {
        unsigned int p = packed[j];
        int pos = atomicAdd(&cur[p >> 24], 1);
        ssrc[pos] = (int)(p & SRC_MASK);
    }
}

// Mean aggregation over bf16 features: 8 lanes per node (16B each), 8x
// unroll -> up to 64 independent 16B requests in flight per wave.
__global__ __launch_bounds__(256) void agg_bf16_kernel(
    const unsigned short* __restrict__ featb,   // [N][64] bf16
    const int* __restrict__ rowptr,
    const int* __restrict__ ssrc,
    unsigned short* __restrict__ meanb,         // [N][64] bf16
    int nNodes) {
    int tid = blockIdx.x * blockDim.x + threadIdx.x;
    int node = tid >> 3;
    if (node >= nNodes) return;
    int chunk = tid & 7;  // 8 lanes/node, 16B (8 bf16) each
    const uint4* feat16 = (const uint4*)featb;  // row = 8 x uint4

    int beg = rowptr[node];
    int end = rowptr[node + 1];
    float acc0 = 0.f, acc1 = 0.f, acc2 = 0.f, acc3 = 0.f;
    float acc4 = 0.f, acc5 = 0.f, acc6 = 0.f, acc7 = 0.f;

#define ADDROW(a)                                         \
    acc0 += __uint_as_float((a).x << 16);                 \
    acc1 += __uint_as_float((a).x & 0xffff0000u);         \
    acc2 += __uint_as_float((a).y << 16);                 \
    acc3 += __uint_as_float((a).y & 0xffff0000u);         \
    acc4 += __uint_as_float((a).z << 16);                 \
    acc5 += __uint_as_float((a).z & 0xffff0000u);         \
    acc6 += __uint_as_float((a).w << 16);                 \
    acc7 += __uint_as_float((a).w & 0xffff0000u);

    int j = beg;
    for (; j + 8 <= end; j += 8) {
        int s0 = ssrc[j + 0];
        int s1 = ssrc[j + 1];
        int s2 = ssrc[j + 2];
        int s3 = ssrc[j + 3];
        int s4 = ssrc[j + 4];
        int s5 = ssrc[j + 5];
        int s6 = ssrc[j + 6];
        int s7 = ssrc[j + 7];
        uint4 a0 = feat16[(size_t)s0 * 8 + chunk];
        uint4 a1 = feat16[(size_t)s1 * 8 + chunk];
        uint4 a2 = feat16[(size_t)s2 * 8 + chunk];
        uint4 a3 = feat16[(size_t)s3 * 8 + chunk];
        uint4 a4 = feat16[(size_t)s4 * 8 + chunk];
        uint4 a5 = feat16[(size_t)s5 * 8 + chunk];
        uint4 a6 = feat16[(size_t)s6 * 8 + chunk];
        uint4 a7 = feat16[(size_t)s7 * 8 + chunk];
        ADDROW(a0) ADDROW(a1) ADDROW(a2) ADDROW(a3)
        ADDROW(a4) ADDROW(a5) ADDROW(a6) ADDROW(a7)
    }
    for (; j + 4 <= end; j += 4) {
        int s0 = ssrc[j + 0];
        int s1 = ssrc[j + 1];
        int s2 = ssrc[j + 2];
        int s3 = ssrc[j + 3];
        uint4 a0 = feat16[(size_t)s0 * 8 + chunk];
        uint4 a1 = feat16[(size_t)s1 * 8 + chunk];
        uint4 a2 = feat16[(size_t)s2 * 8 + chunk];
        uint4 a3 = feat16[(size_t)s3 * 8 + chunk];
        ADDROW(a0) ADDROW(a1) ADDROW(a2) ADDROW(a3)
    }
    for (; j < end; ++j) {
        uint4 a = feat16[(size_t)ssrc[j] * 8 + chunk];
        ADDROW(a)
    }
#undef ADDROW

    int deg = end - beg;
    float inv = 1.0f / (float)(deg > 0 ? deg : 1);
    uint4 r;
    r.x = (unsigned int)f2bf(acc0 * inv) | ((unsigned int)f2bf(acc1 * inv) << 16);
    r.y = (unsigned int)f2bf(acc2 * inv) | ((unsigned int)f2bf(acc3 * inv) << 16);
    r.z = (unsigned int)f2bf(acc4 * inv) | ((unsigned int)f2bf(acc5 * inv) << 16);
    r.w = (unsigned int)f2bf(acc6 * inv) | ((unsigned int)f2bf(acc7 * inv) << 16);
    ((uint4*)meanb)[(size_t)node * 8 + chunk] = r;
}

// ---- MFMA linear: out = relu([mean|x] @ [Wl|Wr]^T + b) ----

__device__ __forceinline__ bf16x8 pack8(const float* __restrict__ p) {
    float4 a = *(const float4*)p;
    float4 b = *(const float4*)(p + 4);
    bf16x8 r;
    r[0] = (short)f2bf(a.x); r[1] = (short)f2bf(a.y);
    r[2] = (short)f2bf(a.z); r[3] = (short)f2bf(a.w);
    r[4] = (short)f2bf(b.x); r[5] = (short)f2bf(b.y);
    r[6] = (short)f2bf(b.z); r[7] = (short)f2bf(b.w);
    return r;
}

template <bool OUT_BF16>
__global__ __launch_bounds__(256) void mfma_linear_kernel(
    const unsigned short* __restrict__ meanb,  // [N][64] bf16
    const unsigned short* __restrict__ xb,     // [N][64] bf16
    const float* __restrict__ Wl,
    const float* __restrict__ bias,
    const float* __restrict__ Wr,
    void* __restrict__ outp,
    int nGroups) {
    const int lane = (int)(threadIdx.x & 63);
    const int col = lane & 15;
    const int kg = lane >> 4;

    bf16x8 bfr[4][4];
#pragma unroll
    for (int t = 0; t < 4; ++t) {
        const int n = t * 16 + col;
#pragma unroll
        for (int kk = 0; kk < 4; ++kk) {
            const float* w = (kk < 2 ? Wl : Wr) + n * 64 + (kk & 1) * 32 + kg * 8;
            bfr[t][kk] = pack8(w);
        }
    }
    float bv[4];
#pragma unroll
    for (int t = 0; t < 4; ++t) bv[t] = bias[t * 16 + col];

    const int wave = (int)((blockIdx.x * blockDim.x + threadIdx.x) >> 6);
    const int nWaves = (int)((gridDim.x * blockDim.x) >> 6);

    for (int g = wave; g < nGroups; g += nWaves) {
        const int arow = g * 16 + col;
        const unsigned short* mrow = meanb + (size_t)arow * FEAT + kg * 8;
        const unsigned short* xrow = xb + (size_t)arow * FEAT + kg * 8;

        f32x4 acc[4];
#pragma unroll
        for (int t = 0; t < 4; ++t) acc[t] = (f32x4){0.f, 0.f, 0.f, 0.f};

#pragma unroll
        for (int kk = 0; kk < 4; ++kk) {
            const unsigned short* p =
                (kk < 2) ? (mrow + (kk & 1) * 32) : (xrow + (kk & 1) * 32);
            bf16x8 a = *(const bf16x8*)p;
#pragma unroll
            for (int t = 0; t < 4; ++t)
                acc[t] = __builtin_amdgcn_mfma_f32_16x16x32_bf16(a, bfr[t][kk], acc[t], 0, 0, 0);
        }

#pragma unroll
        for (int t = 0; t < 4; ++t) {
#pragma unroll
            for (int r = 0; r < 4; ++r) {
                int node = g * 16 + kg * 4 + r;
                float v = fmaxf(acc[t][r] + bv[t], 0.0f);
                if (OUT_BF16)
                    ((unsigned short*)outp)[(size_t)node * FEAT + t * 16 + col] = f2bf(v);
                else
                    ((float*)outp)[(size_t)node * FEAT + t * 16 + col] = v;
            }
        }
    }
}

extern "C" void kernel_launch(void* const* d_in, const int* in_sizes, int n_in,
                              void* d_out, int out_size, void* d_ws, size_t ws_size,
                              hipStream_t stream) {
    const float* x   = (const float*)d_in[0];
    const int* ei    = (const int*)d_in[1];
    const float* Wl1 = (const float*)d_in[2];
    const float* b1  = (const float*)d_in[3];
    const float* Wr1 = (const float*)d_in[4];
    const float* Wl2 = (const float*)d_in[5];
    const float* b2  = (const float*)d_in[6];
    const float* Wr2 = (const float*)d_in[7];

    const int E = in_sizes[1] / 2;  // 1,600,000
    const int* src = ei;
    const int* dst = ei + E;
    const int N = N_NODES;

    const int n2 = NBINS * NTILES;               // 100096
    const int TE = (E + NTILES - 1) / NTILES;    // 6250
    const int NB2 = (n2 + SCAN_B - 1) / SCAN_B;  // 98

    // workspace layout (int-counts %4==0 -> every bf16 buffer 16B-aligned)
    int* H      = (int*)d_ws;                            // n2
    int* P      = H + n2;                                // n2+8
    int* bsum   = P + (n2 + 8);                          // 128
    unsigned int* packed = (unsigned int*)(bsum + 128);  // E
    int* rowptr = (int*)(packed + E);                    // N+8
    int* ssrc   = rowptr + (N + 8);                      // E
    unsigned short* meanb = (unsigned short*)(ssrc + E); // N*64 bf16
    unsigned short* xb    = meanb + (size_t)N * FEAT;    // N*64 bf16
    unsigned short* hb    = xb + (size_t)N * FEAT;       // N*64 bf16
    float* out  = (float*)d_out;

    const int NG = N / 16;  // 6250 MFMA node-groups

    // ---- feature conversion + partition/sort (reused by both layers) ----
    cvt_bf16_kernel<<<(N * FEAT / 8 + 255) / 256, 256, 0, stream>>>(x, xb, N * FEAT / 8);
    tile_hist_kernel<<<NTILES, 256, 0, stream>>>(dst, H, E, TE);
    scan1_kernel<<<NB2, SCAN_B, 0, stream>>>(H, P, bsum, n2);
    scan2_kernel<<<1, 128, 0, stream>>>(bsum, NB2);
    scan3_kernel<<<(n2 + 256) / 256, 256, 0, stream>>>(P, bsum, n2, E);
    scatter_bucket_kernel<<<NTILES, 256, 0, stream>>>(src, dst, P, packed, E, TE);
    bucket_sort_kernel<<<NBINS, 256, 0, stream>>>(packed, P, rowptr, ssrc, E);

    // ---- layer 1 ----
    agg_bf16_kernel<<<(N * 8 + 255) / 256, 256, 0, stream>>>(xb, rowptr, ssrc, meanb, N);
    mfma_linear_kernel<true><<<256, 256, 0, stream>>>(meanb, xb, Wl1, b1, Wr1, hb, NG);

    // ---- layer 2 ----
    agg_bf16_kernel<<<(N * 8 + 255) / 256, 256, 0, stream>>>(hb, rowptr, ssrc, meanb, N);
    mfma_linear_kernel<false><<<256, 256, 0, stream>>>(meanb, hb, Wl2, b2, Wr2, out, NG);
}